// Round 1
// baseline (932.635 us; speedup 1.0000x reference)
//
#include <hip/hip_runtime.h>

#define Bb 8
#define Nn 1025
#define Hh 12
#define HD 64
#define DIMC 768
#define MROWS (Bb * Nn)   // 8200
#define SCALE 0.125f

typedef _Float16 f16x8 __attribute__((ext_vector_type(8)));
typedef _Float16 f16x4 __attribute__((ext_vector_type(4)));
typedef float f32x4 __attribute__((ext_vector_type(4)));

// ---------------- fp32 -> fp16 convert (vectorized x4) ----------------
__global__ void cvt_kernel(const float* __restrict__ src, _Float16* __restrict__ dst, int n4) {
    int i = blockIdx.x * 256 + threadIdx.x;
    if (i >= n4) return;
    float4 v = ((const float4*)src)[i];
    f16x4 h;
    h.x = (_Float16)v.x; h.y = (_Float16)v.y; h.z = (_Float16)v.z; h.w = (_Float16)v.w;
    ((f16x4*)dst)[i] = h;
}

// ---------------- MFMA GEMM: C[M x Nc] = A[M x K] * W[Nc x K]^T ----------------
// MODE 0: scatter-write q/k/v fp16 in [B,H,N,64];  MODE 1: write fp32 out + bias
template <int MODE>
__global__ void __launch_bounds__(256) gemm_kernel(
    const _Float16* __restrict__ A, const _Float16* __restrict__ W,
    int M, int Ncols, int K,
    _Float16* __restrict__ outq, _Float16* __restrict__ outk, _Float16* __restrict__ outv,
    const float* __restrict__ bias, float* __restrict__ outf)
{
    __shared__ _Float16 As[128][40];  // +8 pad -> 2-way (free) LDS banking
    __shared__ _Float16 Ws[128][40];
    const int tid = threadIdx.x;
    const int wid = tid >> 6, lane = tid & 63;
    const int quad = lane >> 4, l16 = lane & 15;
    const int bm = blockIdx.x * 128, bn = blockIdx.y * 128;
    const int wm = (wid >> 1) * 64, wn = (wid & 1) * 64;
    const int r0 = tid >> 2, sg = tid & 3;

    f32x4 acc[4][4] = {};

    for (int kk = 0; kk < K; kk += 32) {
#pragma unroll
        for (int i = 0; i < 2; ++i) {
            int r = r0 + i * 64;
            int gr = bm + r;
            f16x8 av = {};
            if (gr < M) av = *(const f16x8*)(A + (size_t)gr * K + kk + sg * 8);
            *(f16x8*)&As[r][sg * 8] = av;
            int gc = bn + r;
            f16x8 wv = {};
            if (gc < Ncols) wv = *(const f16x8*)(W + (size_t)gc * K + kk + sg * 8);
            *(f16x8*)&Ws[r][sg * 8] = wv;
        }
        __syncthreads();
        f16x8 af[4], bf[4];
#pragma unroll
        for (int t = 0; t < 4; ++t) {
            af[t] = *(const f16x8*)&As[wm + t * 16 + l16][quad * 8];
            bf[t] = *(const f16x8*)&Ws[wn + t * 16 + l16][quad * 8];
        }
#pragma unroll
        for (int tm = 0; tm < 4; ++tm)
#pragma unroll
            for (int tn = 0; tn < 4; ++tn)
                acc[tm][tn] = __builtin_amdgcn_mfma_f32_16x16x32_f16(af[tm], bf[tn], acc[tm][tn], 0, 0, 0);
        __syncthreads();
    }

    // epilogue: D[row][col], row = bm+wm+tm*16+quad*4+r, col = bn+wn+tn*16+l16
#pragma unroll
    for (int tm = 0; tm < 4; ++tm) {
#pragma unroll
        for (int r = 0; r < 4; ++r) {
            int row = bm + wm + tm * 16 + quad * 4 + r;
            if (row >= M) continue;
#pragma unroll
            for (int tn = 0; tn < 4; ++tn) {
                int col = bn + wn + tn * 16 + l16;
                float val = acc[tm][tn][r];
                if (MODE == 0) {
                    int s = col / DIMC;
                    int rem = col - s * DIMC;
                    int h = rem >> 6, d = rem & 63;
                    int b = row / Nn, n = row - b * Nn;
                    size_t dst = (((size_t)b * Hh + h) * Nn + n) * HD + d;
                    _Float16 hv = (_Float16)val;
                    if (s == 0) outq[dst] = hv;
                    else if (s == 1) outk[dst] = hv;
                    else outv[dst] = hv;
                } else {
                    outf[(size_t)row * DIMC + col] = val + bias[col];
                }
            }
        }
    }
}

// ---------------- RoPE-2D in place + cls row/col pre-dots ----------------
// one wave per (b,h,n). col0[bh*N+n] = q_n . k_0 * scale (un-roped)
//                       row0[bh*N+n] = q_0 . k_n * scale (un-roped)
__global__ void __launch_bounds__(256) rope_kernel(
    _Float16* __restrict__ qh, _Float16* __restrict__ kh,
    const int* __restrict__ xpos, float* __restrict__ col0, float* __restrict__ row0)
{
    int gw = blockIdx.x * 4 + (threadIdx.x >> 6);
    int lane = threadIdx.x & 63;
    if (gw >= Bb * Hh * Nn) return;
    int n = gw % Nn;
    int bh = gw / Nn;
    int b = bh / Hh;
    size_t base = (size_t)bh * Nn * HD;

    float q = (float)qh[base + (size_t)n * HD + lane];
    float k = (float)kh[base + (size_t)n * HD + lane];
    float q0 = (float)qh[base + lane];
    float k0 = (float)kh[base + lane];

    float dcol = q * k0, drow = q0 * k;
#pragma unroll
    for (int off = 1; off < 64; off <<= 1) {
        dcol += __shfl_xor(dcol, off);
        drow += __shfl_xor(drow, off);
    }
    if (lane == 0) {
        col0[gw] = dcol * SCALE;
        row0[gw] = drow * SCALE;
    }

    if (n >= 1) {
        int py = xpos[((size_t)b * Nn + n) * 2 + 0];
        int px = xpos[((size_t)b * Nn + n) * 2 + 1];
        float pos = (lane < 32) ? (float)py : (float)px;
        int j = lane & 15;
        float inv = powf(100.0f, -(float)j * (1.0f / 16.0f));
        float ang = pos * inv;
        float sv, cv;
        sincosf(ang, &sv, &cv);
        float qp = __shfl_xor(q, 16);
        float kp = __shfl_xor(k, 16);
        float sgn = (lane & 16) ? 1.0f : -1.0f;
        float qr = q * cv + sgn * qp * sv;
        float kr = k * cv + sgn * kp * sv;
        qh[base + (size_t)n * HD + lane] = (_Float16)qr;
        kh[base + (size_t)n * HD + lane] = (_Float16)kr;
    }
}

// ---------------- flash attention, BQ=64 (16 rows/wave), KV chunk 128 ----------------
__global__ void __launch_bounds__(256) flash_kernel(
    const _Float16* __restrict__ qh, const _Float16* __restrict__ kh,
    const _Float16* __restrict__ vh, const float* __restrict__ col0,
    const float* __restrict__ row0, _Float16* __restrict__ att)
{
    __shared__ _Float16 Qs[64][72];
    __shared__ _Float16 Ks[128][72];
    __shared__ _Float16 Vt[64][136];      // transposed V: Vt[d][j]
    __shared__ _Float16 Ps[4][16][136];   // per-wave P staging (C-layout -> A-layout)

    const int qt = blockIdx.x, bh = blockIdx.y;
    const int b = bh / Hh, h = bh - b * Hh;
    const int tid = threadIdx.x, wid = tid >> 6, lane = tid & 63;
    const int quad = lane >> 4, l16 = lane & 15;
    const size_t base = (size_t)bh * Nn * HD;
    const int q0row = qt * 64;

    // stage Q tile (zeros beyond N)
#pragma unroll
    for (int i = 0; i < 2; ++i) {
        int sid = tid + i * 256;
        int r = sid >> 3, sg = sid & 7;
        int gr = q0row + r;
        f16x8 v8 = {};
        if (gr < Nn) v8 = *(const f16x8*)(qh + base + (size_t)gr * HD + sg * 8);
        *(f16x8*)&Qs[r][sg * 8] = v8;
    }

    f32x4 oacc[4] = {};
    float mrow[4], lrow[4];
#pragma unroll
    for (int r = 0; r < 4; ++r) { mrow[r] = -1e30f; lrow[r] = 0.f; }

    for (int c0 = 0; c0 < Nn; c0 += 128) {
        // stage K chunk
#pragma unroll
        for (int i = 0; i < 4; ++i) {
            int sid = tid + i * 256;
            int r = sid >> 3, sg = sid & 7;
            int gr = c0 + r;
            f16x8 v8 = {};
            if (gr < Nn) v8 = *(const f16x8*)(kh + base + (size_t)gr * HD + sg * 8);
            *(f16x8*)&Ks[r][sg * 8] = v8;
        }
        // stage V transposed
#pragma unroll
        for (int i = 0; i < 32; ++i) {
            int e = tid + i * 256;
            int j = e >> 6, d = e & 63;
            int gr = c0 + j;
            _Float16 vv = (_Float16)0.f;
            if (gr < Nn) vv = vh[base + (size_t)gr * HD + d];
            Vt[d][j] = vv;
        }
        __syncthreads();

        // S = Q K^T  (16 rows x 128 cols per wave)
        f32x4 sacc[8] = {};
#pragma unroll
        for (int ks = 0; ks < 2; ++ks) {
            f16x8 aq = *(const f16x8*)&Qs[wid * 16 + l16][ks * 32 + quad * 8];
#pragma unroll
            for (int ct = 0; ct < 8; ++ct) {
                f16x8 bk = *(const f16x8*)&Ks[ct * 16 + l16][ks * 32 + quad * 8];
                sacc[ct] = __builtin_amdgcn_mfma_f32_16x16x32_f16(aq, bk, sacc[ct], 0, 0, 0);
            }
        }

        // scale + cls-row/col overrides + OOB
        float sv[8][4];
        const int gibase = q0row + wid * 16 + quad * 4;
#pragma unroll
        for (int ct = 0; ct < 8; ++ct) {
            int gj = c0 + ct * 16 + l16;
#pragma unroll
            for (int r = 0; r < 4; ++r) {
                int gi = gibase + r;
                float s = sacc[ct][r] * SCALE;
                if (gj == 0) s = col0[bh * Nn + (gi < Nn ? gi : Nn - 1)];
                if (gi == 0 && gj < Nn) s = row0[bh * Nn + gj];
                if (gj >= Nn) s = -1e30f;
                sv[ct][r] = s;
            }
        }

        // online softmax update (rows live in quads; reduce over l16 lanes)
#pragma unroll
        for (int r = 0; r < 4; ++r) {
            float mx = sv[0][r];
#pragma unroll
            for (int ct = 1; ct < 8; ++ct) mx = fmaxf(mx, sv[ct][r]);
#pragma unroll
            for (int off = 1; off < 16; off <<= 1) mx = fmaxf(mx, __shfl_xor(mx, off));
            float mnew = fmaxf(mrow[r], mx);
            float alpha = __expf(mrow[r] - mnew);
            mrow[r] = mnew;
            float rs = 0.f;
#pragma unroll
            for (int ct = 0; ct < 8; ++ct) {
                float p = __expf(sv[ct][r] - mnew);
                sv[ct][r] = p;
                rs += p;
            }
#pragma unroll
            for (int off = 1; off < 16; off <<= 1) rs += __shfl_xor(rs, off);
            lrow[r] = lrow[r] * alpha + rs;
#pragma unroll
            for (int ct = 0; ct < 4; ++ct) oacc[ct][r] *= alpha;
        }

        // P: C-layout -> LDS -> A-layout
#pragma unroll
        for (int ct = 0; ct < 8; ++ct)
#pragma unroll
            for (int r = 0; r < 4; ++r)
                Ps[wid][quad * 4 + r][ct * 16 + l16] = (_Float16)sv[ct][r];
        __syncthreads();

        // O += P @ V
#pragma unroll
        for (int ks = 0; ks < 4; ++ks) {
            f16x8 ap = *(const f16x8*)&Ps[wid][l16][ks * 32 + quad * 8];
#pragma unroll
            for (int ct = 0; ct < 4; ++ct) {
                f16x8 bv = *(const f16x8*)&Vt[ct * 16 + l16][ks * 32 + quad * 8];
                oacc[ct] = __builtin_amdgcn_mfma_f32_16x16x32_f16(ap, bv, oacc[ct], 0, 0, 0);
            }
        }
        __syncthreads();
    }

    // epilogue: att[b, n, h*64 + d]
#pragma unroll
    for (int r = 0; r < 4; ++r) {
        int gi = q0row + wid * 16 + quad * 4 + r;
        if (gi >= Nn) continue;
        float inv_l = 1.0f / lrow[r];
#pragma unroll
        for (int ct = 0; ct < 4; ++ct) {
            att[((size_t)b * Nn + gi) * DIMC + h * HD + ct * 16 + l16] =
                (_Float16)(oacc[ct][r] * inv_l);
        }
    }
}

extern "C" void kernel_launch(void* const* d_in, const int* in_sizes, int n_in,
                              void* d_out, int out_size, void* d_ws, size_t ws_size,
                              hipStream_t stream) {
    const float* x      = (const float*)d_in[1];
    const int*   xpos   = (const int*)d_in[2];
    const float* w_qkv  = (const float*)d_in[4];
    const float* w_proj = (const float*)d_in[5];
    const float* b_proj = (const float*)d_in[6];
    float* out = (float*)d_out;

    char* ws = (char*)d_ws;
    size_t off = 0;
    auto alloc = [&](size_t bytes) {
        char* p = ws + off;
        off += (bytes + 255) & ~(size_t)255;
        return p;
    };
    const size_t QKV_ELEMS = (size_t)Bb * Hh * Nn * HD;      // 6,297,600
    _Float16* xh     = (_Float16*)alloc((size_t)MROWS * DIMC * 2);
    _Float16* qh     = (_Float16*)alloc(QKV_ELEMS * 2);
    _Float16* kh     = (_Float16*)alloc(QKV_ELEMS * 2);
    _Float16* vh     = (_Float16*)alloc(QKV_ELEMS * 2);
    _Float16* wqkvh  = (_Float16*)alloc((size_t)3 * DIMC * DIMC * 2);
    _Float16* wprojh = (_Float16*)alloc((size_t)DIMC * DIMC * 2);
    float* col0      = (float*)alloc((size_t)Bb * Hh * Nn * 4);
    float* row0      = (float*)alloc((size_t)Bb * Hh * Nn * 4);
    _Float16* atth   = xh;  // alias: x consumed by QKV GEMM before flash writes att

    // converts
    {
        int n4 = (MROWS * DIMC) / 4;
        cvt_kernel<<<(n4 + 255) / 256, 256, 0, stream>>>(x, xh, n4);
    }
    {
        int n4 = (3 * DIMC * DIMC) / 4;
        cvt_kernel<<<(n4 + 255) / 256, 256, 0, stream>>>(w_qkv, wqkvh, n4);
    }
    {
        int n4 = (DIMC * DIMC) / 4;
        cvt_kernel<<<(n4 + 255) / 256, 256, 0, stream>>>(w_proj, wprojh, n4);
    }

    // QKV projection: M=8200, Nc=2304, K=768
    gemm_kernel<0><<<dim3((MROWS + 127) / 128, (3 * DIMC) / 128), 256, 0, stream>>>(
        xh, wqkvh, MROWS, 3 * DIMC, DIMC, qh, kh, vh, nullptr, nullptr);

    // RoPE + cls dots: one wave per (b,h,n)
    rope_kernel<<<(Bb * Hh * Nn) / 4, 256, 0, stream>>>(qh, kh, xpos, col0, row0);

    // flash attention: 17 q-tiles x 96 (b,h)
    flash_kernel<<<dim3((Nn + 63) / 64, Bb * Hh), 256, 0, stream>>>(
        qh, kh, vh, col0, row0, atth);

    // out projection: M=8200, Nc=768, K=768 (+bias) -> fp32
    gemm_kernel<1><<<dim3((MROWS + 127) / 128, DIMC / 128), 256, 0, stream>>>(
        atth, wprojh, MROWS, DIMC, DIMC, nullptr, nullptr, nullptr, b_proj, out);
}